// Round 1
// baseline (233.822 us; speedup 1.0000x reference)
//
#include <hip/hip_runtime.h>

// ---------------------------------------------------------------------------
// SwitchHeadAttention: x@Wq -> Q, x@Wkv -> K,V ; flash attention ; per-head
// output projection with Wo + bo.  B=2 T=2048 DIM=1024 H=16 DH=64.
// All matmuls in bf16 MFMA (16x16x32) with fp32 accumulation.
// ---------------------------------------------------------------------------

typedef __attribute__((ext_vector_type(8))) short bf16x8;
typedef __attribute__((ext_vector_type(4))) float f32x4;

#define MFMA16(a, b, c) __builtin_amdgcn_mfma_f32_16x16x32_bf16((a), (b), (c), 0, 0, 0)

#define B_    2
#define T_    2048
#define DIM_  1024
#define H_    16
#define DH_   64

__device__ inline unsigned short f2bf(float x) {
    union { float f; unsigned int u; } c; c.f = x;
    unsigned int r = c.u + 0x7FFFu + ((c.u >> 16) & 1u);   // RNE
    return (unsigned short)(r >> 16);
}

// -------------------- convert x (fp32 -> bf16), 4 elems/thread -------------
__global__ __launch_bounds__(256) void cvt_x_kernel(const float* __restrict__ x,
                                                    unsigned short* __restrict__ xb,
                                                    int n4) {
    int i = blockIdx.x * 256 + threadIdx.x;
    if (i >= n4) return;
    const float4 v = reinterpret_cast<const float4*>(x)[i];
    union { unsigned short h[4]; uint2 u; } o;
    o.h[0] = f2bf(v.x); o.h[1] = f2bf(v.y); o.h[2] = f2bf(v.z); o.h[3] = f2bf(v.w);
    reinterpret_cast<uint2*>(xb)[i] = o.u;
}

// ------------- transpose + convert weights: src[R][C] -> dst[C][R] ---------
__global__ __launch_bounds__(256) void transpose_cvt_kernel(const float* __restrict__ src,
                                                            unsigned short* __restrict__ dst,
                                                            int R, int C, float scale) {
    __shared__ float tile[32][33];
    int bc = blockIdx.x * 32, br = blockIdx.y * 32;
    int tx = threadIdx.x & 31, ty = threadIdx.x >> 5;   // 32 x 8
    for (int i = ty; i < 32; i += 8)
        tile[i][tx] = src[(size_t)(br + i) * C + bc + tx];
    __syncthreads();
    for (int i = ty; i < 32; i += 8)
        dst[(size_t)(bc + i) * R + br + tx] = f2bf(tile[tx][i] * scale);
}

// --------- Wo[h][d][e] -> WoT[h][e][d] bf16 (65536 elements) ---------------
__global__ __launch_bounds__(256) void cvt_wo_kernel(const float* __restrict__ wo,
                                                     unsigned short* __restrict__ wot) {
    int i = blockIdx.x * 256 + threadIdx.x;          // i = h*4096 + e*64 + d
    int h = i >> 12, e = (i >> 6) & 63, d = i & 63;
    wot[i] = f2bf(wo[(h << 12) + (d << 6) + e]);
}

// -------------------- fused QKV GEMM:  [4096x1024] @ [1024x3072] -----------
// A = xb row-major, B = wt[n][k] (pre-transposed).  Tile 128x128, BK=64.
// Epilogue scatters into Q/K/V buffers laid out [b][h][t][d] (bf16).
// Wq columns were pre-scaled by DH^-0.5 so Q is already scaled.
__global__ __launch_bounds__(256) void qkv_gemm_kernel(const unsigned short* __restrict__ xb,
                                                       const unsigned short* __restrict__ wt,
                                                       unsigned short* __restrict__ qb,
                                                       unsigned short* __restrict__ kb,
                                                       unsigned short* __restrict__ vb) {
    __shared__ unsigned short As[128][72];
    __shared__ unsigned short Bs[128][72];
    const int tid  = threadIdx.x;
    const int lane = tid & 63, wv = tid >> 6;
    const int lr = lane & 15, lg = lane >> 4;
    const int bm = (int)(blockIdx.x & 31) * 128;   // 32 M-tiles
    const int bn = (int)(blockIdx.x >> 5) * 128;   // 24 N-tiles
    const int wm = (wv >> 1) * 64, wn = (wv & 1) * 64;
    const int srow = tid >> 3, skoff = (tid & 7) * 8;

    f32x4 acc[4][4] = {};

    for (int k0 = 0; k0 < DIM_; k0 += 64) {
        __syncthreads();
#pragma unroll
        for (int i = 0; i < 4; i++) {
            int row = srow + i * 32;
            *reinterpret_cast<int4*>(&As[row][skoff]) =
                *reinterpret_cast<const int4*>(xb + (size_t)(bm + row) * DIM_ + k0 + skoff);
            *reinterpret_cast<int4*>(&Bs[row][skoff]) =
                *reinterpret_cast<const int4*>(wt + (size_t)(bn + row) * DIM_ + k0 + skoff);
        }
        __syncthreads();

        bf16x8 a[4][2], b[4][2];
#pragma unroll
        for (int mi = 0; mi < 4; mi++) {
            a[mi][0] = *reinterpret_cast<const bf16x8*>(&As[wm + mi * 16 + lr][lg * 8]);
            a[mi][1] = *reinterpret_cast<const bf16x8*>(&As[wm + mi * 16 + lr][32 + lg * 8]);
        }
#pragma unroll
        for (int nj = 0; nj < 4; nj++) {
            b[nj][0] = *reinterpret_cast<const bf16x8*>(&Bs[wn + nj * 16 + lr][lg * 8]);
            b[nj][1] = *reinterpret_cast<const bf16x8*>(&Bs[wn + nj * 16 + lr][32 + lg * 8]);
        }
#pragma unroll
        for (int ks = 0; ks < 2; ks++)
#pragma unroll
            for (int mi = 0; mi < 4; mi++)
#pragma unroll
                for (int nj = 0; nj < 4; nj++)
                    acc[mi][nj] = MFMA16(a[mi][ks], b[nj][ks], acc[mi][nj]);
    }

    // epilogue: m -> (b,t); n -> {Q,K,V} x (h,d)
#pragma unroll
    for (int mi = 0; mi < 4; mi++) {
        int m  = bm + wm + mi * 16 + lg * 4;   // row for rr=0
        int bb = m >> 11, t = m & 2047;
#pragma unroll
        for (int nj = 0; nj < 4; nj++) {
            int n = bn + wn + nj * 16 + lr;
            unsigned short* dst; int n2;
            if      (n < 1024) { dst = qb; n2 = n; }
            else if (n < 2048) { dst = kb; n2 = n - 1024; }
            else               { dst = vb; n2 = n - 2048; }
            int h = n2 >> 6, d = n2 & 63;
            size_t base = ((size_t)((bb << 4) + h) * T_ + t) * DH_ + d;
#pragma unroll
            for (int rr = 0; rr < 4; rr++)
                dst[base + (size_t)rr * DH_] = f2bf(acc[mi][nj][rr]);
        }
    }
}

// -------------------- flash attention + fused output projection ------------
// grid = B*H*(T/128) = 512 blocks; 4 waves, each owns 32 q-rows.
__global__ __launch_bounds__(256) void attn_kernel(const unsigned short* __restrict__ qb,
                                                   const unsigned short* __restrict__ kb,
                                                   const unsigned short* __restrict__ vb,
                                                   const unsigned short* __restrict__ wot,
                                                   const float* __restrict__ bo,
                                                   float* __restrict__ out) {
    __shared__ unsigned short Ks[64][72];        // K tile  [key][d]
    __shared__ unsigned short Vt[64][72];        // V tile transposed [d][key]
    __shared__ unsigned short Ps[4][32][72];     // per-wave P / O roundtrip
    __shared__ unsigned short Wos[64][72];       // Wo^T[h]  [e][d]

    const int tid  = threadIdx.x;
    const int lane = tid & 63, wv = tid >> 6;
    const int lr = lane & 15, lg = lane >> 4;
    const int blk = blockIdx.x;
    const int qt = blk & 15;                     // q tile
    const int bh = blk >> 4;                     // 0..31
    const int b  = bh >> 4, h = bh & 15;

    const unsigned short* Qp = qb + (size_t)bh * T_ * DH_;
    const unsigned short* Kp = kb + (size_t)bh * T_ * DH_;
    const unsigned short* Vp = vb + (size_t)bh * T_ * DH_;

    // stage Wo^T for this head (read after K-loop; first barrier orders it)
    for (int i = tid; i < 512; i += 256) {
        int r = i >> 3, c8 = (i & 7) * 8;
        *reinterpret_cast<int4*>(&Wos[r][c8]) =
            *reinterpret_cast<const int4*>(wot + ((size_t)h << 12) + (r << 6) + c8);
    }

    const int qrow0 = qt * 128 + wv * 32;
    bf16x8 qf[2][2];
#pragma unroll
    for (int mi = 0; mi < 2; mi++)
#pragma unroll
        for (int ks = 0; ks < 2; ks++)
            qf[mi][ks] = *reinterpret_cast<const bf16x8*>(
                Qp + (size_t)(qrow0 + mi * 16 + lr) * DH_ + ks * 32 + lg * 8);

    float m_r[2][4], l_r[2][4];
    f32x4 o_acc[2][4] = {};
#pragma unroll
    for (int mi = 0; mi < 2; mi++)
#pragma unroll
        for (int rr = 0; rr < 4; rr++) { m_r[mi][rr] = -1e30f; l_r[mi][rr] = 0.f; }

    for (int kt = 0; kt < T_; kt += 64) {
        __syncthreads();
        for (int i = tid; i < 512; i += 256) {
            int key = i >> 3, d8 = (i & 7) * 8;
            *reinterpret_cast<int4*>(&Ks[key][d8]) =
                *reinterpret_cast<const int4*>(Kp + (size_t)(kt + key) * DH_ + d8);
            bf16x8 vvv = *reinterpret_cast<const bf16x8*>(Vp + (size_t)(kt + key) * DH_ + d8);
#pragma unroll
            for (int j = 0; j < 8; j++)
                Vt[d8 + j][key] = (unsigned short)vvv[j];
        }
        __syncthreads();

        // ---- S = Q K^T (rows: q, cols: key) ----
        f32x4 s[2][4] = {};
#pragma unroll
        for (int ks = 0; ks < 2; ks++)
#pragma unroll
            for (int nj = 0; nj < 4; nj++) {
                bf16x8 kf = *reinterpret_cast<const bf16x8*>(&Ks[nj * 16 + lr][ks * 32 + lg * 8]);
                s[0][nj] = MFMA16(qf[0][ks], kf, s[0][nj]);
                s[1][nj] = MFMA16(qf[1][ks], kf, s[1][nj]);
            }

        // ---- online softmax (row-wise over 64 keys) ----
#pragma unroll
        for (int mi = 0; mi < 2; mi++)
#pragma unroll
            for (int rr = 0; rr < 4; rr++) {
                float tmax = fmaxf(fmaxf(s[mi][0][rr], s[mi][1][rr]),
                                   fmaxf(s[mi][2][rr], s[mi][3][rr]));
#pragma unroll
                for (int off = 1; off < 16; off <<= 1)
                    tmax = fmaxf(tmax, __shfl_xor(tmax, off));
                float mold = m_r[mi][rr];
                float mnew = fmaxf(mold, tmax);
                float scl  = exp2f((mold - mnew) * 1.44269504089f);
                m_r[mi][rr] = mnew;
                float tsum = 0.f;
#pragma unroll
                for (int nj = 0; nj < 4; nj++) {
                    float p = exp2f((s[mi][nj][rr] - mnew) * 1.44269504089f);
                    s[mi][nj][rr] = p;
                    tsum += p;
                }
#pragma unroll
                for (int off = 1; off < 16; off <<= 1)
                    tsum += __shfl_xor(tsum, off);
                l_r[mi][rr] = l_r[mi][rr] * scl + tsum;
#pragma unroll
                for (int dj = 0; dj < 4; dj++)
                    o_acc[mi][dj][rr] *= scl;
            }

        // ---- P -> LDS (re-enter A-operand layout) ----
#pragma unroll
        for (int mi = 0; mi < 2; mi++)
#pragma unroll
            for (int nj = 0; nj < 4; nj++)
#pragma unroll
                for (int rr = 0; rr < 4; rr++)
                    Ps[wv][mi * 16 + lg * 4 + rr][nj * 16 + lr] = f2bf(s[mi][nj][rr]);

        // ---- O += P V ----
#pragma unroll
        for (int ks = 0; ks < 2; ks++) {
            bf16x8 vf[4];
#pragma unroll
            for (int dj = 0; dj < 4; dj++)
                vf[dj] = *reinterpret_cast<const bf16x8*>(&Vt[dj * 16 + lr][ks * 32 + lg * 8]);
#pragma unroll
            for (int mi = 0; mi < 2; mi++) {
                bf16x8 pf = *reinterpret_cast<const bf16x8*>(&Ps[wv][mi * 16 + lr][ks * 32 + lg * 8]);
#pragma unroll
                for (int dj = 0; dj < 4; dj++)
                    o_acc[mi][dj] = MFMA16(pf, vf[dj], o_acc[mi][dj]);
            }
        }
    }

    // ---- normalize, O -> LDS ----
#pragma unroll
    for (int mi = 0; mi < 2; mi++)
#pragma unroll
        for (int rr = 0; rr < 4; rr++) {
            float inv = 1.f / l_r[mi][rr];
#pragma unroll
            for (int dj = 0; dj < 4; dj++)
                Ps[wv][mi * 16 + lg * 4 + rr][dj * 16 + lr] = f2bf(o_acc[mi][dj][rr] * inv);
        }

    // ---- Y = O @ Wo[h] ----
    f32x4 y[2][4] = {};
#pragma unroll
    for (int ks = 0; ks < 2; ks++) {
        bf16x8 wf[4];
#pragma unroll
        for (int ej = 0; ej < 4; ej++)
            wf[ej] = *reinterpret_cast<const bf16x8*>(&Wos[ej * 16 + lr][ks * 32 + lg * 8]);
#pragma unroll
        for (int mi = 0; mi < 2; mi++) {
            bf16x8 of = *reinterpret_cast<const bf16x8*>(&Ps[wv][mi * 16 + lr][ks * 32 + lg * 8]);
#pragma unroll
            for (int ej = 0; ej < 4; ej++)
                y[mi][ej] = MFMA16(of, wf[ej], y[mi][ej]);
        }
    }

    // ---- bias + store fp32 out[b][t][h*64+e] ----
#pragma unroll
    for (int mi = 0; mi < 2; mi++)
#pragma unroll
        for (int ej = 0; ej < 4; ej++) {
            float bias = bo[(h << 6) + ej * 16 + lr];
#pragma unroll
            for (int rr = 0; rr < 4; rr++) {
                int t = qrow0 + mi * 16 + lg * 4 + rr;
                out[((size_t)b * T_ + t) * (H_ * DH_) + (h << 6) + ej * 16 + lr] =
                    y[mi][ej][rr] + bias;
            }
        }
}

// ---------------------------------------------------------------------------
extern "C" void kernel_launch(void* const* d_in, const int* in_sizes, int n_in,
                              void* d_out, int out_size, void* d_ws, size_t ws_size,
                              hipStream_t stream) {
    const float* x   = (const float*)d_in[0];
    const float* Wq  = (const float*)d_in[1];
    const float* Wkv = (const float*)d_in[2];
    const float* Wo  = (const float*)d_in[3];
    const float* bo  = (const float*)d_in[4];
    float* out = (float*)d_out;

    char* ws = (char*)d_ws;
    unsigned short* xb  = (unsigned short*)(ws);                  //  8 MB  x bf16
    unsigned short* wt  = (unsigned short*)(ws + 8388608);        //  6 MB  [Wq^T;Wkv^T]
    unsigned short* wot = (unsigned short*)(ws + 14680064);       // 128 KB Wo^T
    unsigned short* qb  = (unsigned short*)(ws + 14811136);       //  8 MB  Q
    unsigned short* kb  = (unsigned short*)(ws + 23199744);       //  8 MB  K
    unsigned short* vb  = (unsigned short*)(ws + 31588352);       //  8 MB  V

    cvt_x_kernel<<<4096, 256, 0, stream>>>(x, xb, (B_ * T_ * DIM_) / 4);
    // Wq cols pre-scaled by DH^-0.5 = 0.125 (exact in bf16)
    transpose_cvt_kernel<<<dim3(32, 32), 256, 0, stream>>>(Wq, wt, DIM_, 1024, 0.125f);
    transpose_cvt_kernel<<<dim3(64, 32), 256, 0, stream>>>(Wkv, wt + 1024 * 1024, DIM_, 2048, 1.0f);
    cvt_wo_kernel<<<256, 256, 0, stream>>>(Wo, wot);
    qkv_gemm_kernel<<<768, 256, 0, stream>>>(xb, wt, qb, kb, vb);
    attn_kernel<<<512, 256, 0, stream>>>(qb, kb, vb, wot, bo, out);
}

// Round 2
// 176.640 us; speedup vs baseline: 1.3237x; 1.3237x over previous
//
#include <hip/hip_runtime.h>

// ---------------------------------------------------------------------------
// SwitchHeadAttention: x@Wq -> Q, x@Wkv -> K,V ; flash attention ; per-head
// output projection with Wo + bo.  B=2 T=2048 DIM=1024 H=16 DH=64.
// All matmuls in bf16 MFMA (16x16x32) with fp32 accumulation.
// R2: V written pre-transposed by QKV GEMM (kills 16-way LDS conflicts),
//     8-wave attn blocks (occupancy 8->16 waves/CU), reg-prefetch staging,
//     defer-max rescale, XCD-chunked block swizzle.
// ---------------------------------------------------------------------------

typedef __attribute__((ext_vector_type(8))) short bf16x8;
typedef __attribute__((ext_vector_type(4))) float f32x4;

#define MFMA16(a, b, c) __builtin_amdgcn_mfma_f32_16x16x32_bf16((a), (b), (c), 0, 0, 0)

#define B_    2
#define T_    2048
#define DIM_  1024
#define H_    16
#define DH_   64
#define LOG2E 1.44269504089f

__device__ inline unsigned short f2bf(float x) {
    union { float f; unsigned int u; } c; c.f = x;
    unsigned int r = c.u + 0x7FFFu + ((c.u >> 16) & 1u);   // RNE
    return (unsigned short)(r >> 16);
}

// -------------------- convert x (fp32 -> bf16), 4 elems/thread -------------
__global__ __launch_bounds__(256) void cvt_x_kernel(const float* __restrict__ x,
                                                    unsigned short* __restrict__ xb,
                                                    int n4) {
    int i = blockIdx.x * 256 + threadIdx.x;
    if (i >= n4) return;
    const float4 v = reinterpret_cast<const float4*>(x)[i];
    union { unsigned short h[4]; uint2 u; } o;
    o.h[0] = f2bf(v.x); o.h[1] = f2bf(v.y); o.h[2] = f2bf(v.z); o.h[3] = f2bf(v.w);
    reinterpret_cast<uint2*>(xb)[i] = o.u;
}

// ------------- transpose + convert weights: src[R][C] -> dst[C][R] ---------
__global__ __launch_bounds__(256) void transpose_cvt_kernel(const float* __restrict__ src,
                                                            unsigned short* __restrict__ dst,
                                                            int R, int C, float scale) {
    __shared__ float tile[32][33];
    int bc = blockIdx.x * 32, br = blockIdx.y * 32;
    int tx = threadIdx.x & 31, ty = threadIdx.x >> 5;   // 32 x 8
    for (int i = ty; i < 32; i += 8)
        tile[i][tx] = src[(size_t)(br + i) * C + bc + tx];
    __syncthreads();
    for (int i = ty; i < 32; i += 8)
        dst[(size_t)(bc + i) * R + br + tx] = f2bf(tile[tx][i] * scale);
}

// --------- Wo[h][d][e] -> WoT[h][e][d] bf16 (65536 elements) ---------------
__global__ __launch_bounds__(256) void cvt_wo_kernel(const float* __restrict__ wo,
                                                     unsigned short* __restrict__ wot) {
    int i = blockIdx.x * 256 + threadIdx.x;          // i = h*4096 + e*64 + d
    int h = i >> 12, e = (i >> 6) & 63, d = i & 63;
    wot[i] = f2bf(wo[(h << 12) + (d << 6) + e]);
}

// -------------------- fused QKV GEMM:  [4096x1024] @ [1024x3072] -----------
// A = xb row-major, B = wt[n][k] (pre-transposed).  Tile 128x128, BK=64.
// Q, K scatter to [b][h][t][d]; V scatters TRANSPOSED to [b][h][d][t].
// Wq columns were pre-scaled by DH^-0.5 so Q is already scaled.
__global__ __launch_bounds__(256) void qkv_gemm_kernel(const unsigned short* __restrict__ xb,
                                                       const unsigned short* __restrict__ wt,
                                                       unsigned short* __restrict__ qb,
                                                       unsigned short* __restrict__ kb,
                                                       unsigned short* __restrict__ vt) {
    __shared__ unsigned short As[128][72];
    __shared__ unsigned short Bs[128][72];
    const int tid  = threadIdx.x;
    const int lane = tid & 63, wv = tid >> 6;
    const int lr = lane & 15, lg = lane >> 4;
    const int bm = (int)(blockIdx.x & 31) * 128;   // 32 M-tiles
    const int bn = (int)(blockIdx.x >> 5) * 128;   // 24 N-tiles
    const int wm = (wv >> 1) * 64, wn = (wv & 1) * 64;
    const int srow = tid >> 3, skoff = (tid & 7) * 8;

    f32x4 acc[4][4] = {};

    for (int k0 = 0; k0 < DIM_; k0 += 64) {
        __syncthreads();
#pragma unroll
        for (int i = 0; i < 4; i++) {
            int row = srow + i * 32;
            *reinterpret_cast<int4*>(&As[row][skoff]) =
                *reinterpret_cast<const int4*>(xb + (size_t)(bm + row) * DIM_ + k0 + skoff);
            *reinterpret_cast<int4*>(&Bs[row][skoff]) =
                *reinterpret_cast<const int4*>(wt + (size_t)(bn + row) * DIM_ + k0 + skoff);
        }
        __syncthreads();

        bf16x8 a[4][2], b[4][2];
#pragma unroll
        for (int mi = 0; mi < 4; mi++) {
            a[mi][0] = *reinterpret_cast<const bf16x8*>(&As[wm + mi * 16 + lr][lg * 8]);
            a[mi][1] = *reinterpret_cast<const bf16x8*>(&As[wm + mi * 16 + lr][32 + lg * 8]);
        }
#pragma unroll
        for (int nj = 0; nj < 4; nj++) {
            b[nj][0] = *reinterpret_cast<const bf16x8*>(&Bs[wn + nj * 16 + lr][lg * 8]);
            b[nj][1] = *reinterpret_cast<const bf16x8*>(&Bs[wn + nj * 16 + lr][32 + lg * 8]);
        }
#pragma unroll
        for (int ks = 0; ks < 2; ks++)
#pragma unroll
            for (int mi = 0; mi < 4; mi++)
#pragma unroll
                for (int nj = 0; nj < 4; nj++)
                    acc[mi][nj] = MFMA16(a[mi][ks], b[nj][ks], acc[mi][nj]);
    }

    // epilogue: m -> (b,t); n -> {Q,K,V} x (h,d)
#pragma unroll
    for (int mi = 0; mi < 4; mi++) {
        int m  = bm + wm + mi * 16 + lg * 4;   // row for rr=0 (multiple of 4)
        int bb = m >> 11, t = m & 2047;
#pragma unroll
        for (int nj = 0; nj < 4; nj++) {
            int n = bn + wn + nj * 16 + lr;
            if (n < 2048) {
                unsigned short* dst = (n < 1024) ? qb : kb;
                int n2 = n & 1023;
                int h = n2 >> 6, d = n2 & 63;
                size_t base = ((size_t)((bb << 4) + h) * T_ + t) * DH_ + d;
#pragma unroll
                for (int rr = 0; rr < 4; rr++)
                    dst[base + (size_t)rr * DH_] = f2bf(acc[mi][nj][rr]);
            } else {
                int n2 = n - 2048;
                int h = n2 >> 6, d = n2 & 63;
                // V^T layout [b][h][d][t]; 4 consecutive t in one 8B store
                size_t base = ((size_t)((bb << 4) + h) * DH_ + d) * T_ + t;
                union { unsigned short h4[4]; uint2 u; } pk;
#pragma unroll
                for (int rr = 0; rr < 4; rr++) pk.h4[rr] = f2bf(acc[mi][nj][rr]);
                *reinterpret_cast<uint2*>(vt + base) = pk.u;
            }
        }
    }
}

// -------------------- flash attention + fused output projection ------------
// grid = B*H*(T/128) = 512 blocks; 8 waves x 16 q-rows each.
__global__ __launch_bounds__(512) void attn_kernel(const unsigned short* __restrict__ qb,
                                                   const unsigned short* __restrict__ kb,
                                                   const unsigned short* __restrict__ vt,
                                                   const unsigned short* __restrict__ wot,
                                                   const float* __restrict__ bo,
                                                   float* __restrict__ out) {
    __shared__ unsigned short Ks[64][72];        // K tile   [key][d]
    __shared__ unsigned short Vs[64][72];        // V^T tile [d][key]  (pre-transposed)
    __shared__ unsigned short Ps[8][16][72];     // per-wave P / O roundtrip
    __shared__ unsigned short Wos[64][72];       // Wo^T[h]  [e][d]

    const int tid  = threadIdx.x;
    const int lane = tid & 63, wv = tid >> 6;    // 8 waves
    const int lr = lane & 15, lg = lane >> 4;

    // XCD-chunked swizzle: XCD x gets logical blocks [64x, 64x+64) -> the 16
    // q-tiles sharing one head's K/V stay on one XCD's L2.
    const int bid = (int)blockIdx.x;
    const int blk = (bid & 7) * 64 + (bid >> 3);
    const int qt = blk & 15;                     // q tile (128 rows)
    const int bh = blk >> 4;                     // 0..31
    const int b  = bh >> 4, h = bh & 15;

    const unsigned short* Qp  = qb + (size_t)bh * T_ * DH_;
    const unsigned short* Kp  = kb + (size_t)bh * T_ * DH_;
    const unsigned short* Vtp = vt + (size_t)bh * DH_ * T_;

    // stage Wo^T for this head (512 threads cover 64x64 in one shot)
    {
        int r = tid >> 3, c8 = (tid & 7) * 8;
        *reinterpret_cast<int4*>(&Wos[r][c8]) =
            *reinterpret_cast<const int4*>(wot + ((size_t)h << 12) + (r << 6) + c8);
    }

    const int qrow0 = qt * 128 + wv * 16;
    bf16x8 qf[2];
#pragma unroll
    for (int ks = 0; ks < 2; ks++)
        qf[ks] = *reinterpret_cast<const bf16x8*>(
            Qp + (size_t)(qrow0 + lr) * DH_ + ks * 32 + lg * 8);

    float m_r[4], l_r[4];
    f32x4 o_acc[4] = {};
#pragma unroll
    for (int rr = 0; rr < 4; rr++) { m_r[rr] = -1e30f; l_r[rr] = 0.f; }

    // staging coords: 512 threads cover a 64x64 bf16 tile (16B each)
    const int sRow = tid >> 3, sOff = (tid & 7) * 8;

    // prefetch tile 0 into registers
    int4 kReg = *reinterpret_cast<const int4*>(Kp + (size_t)sRow * DH_ + sOff);
    int4 vReg = *reinterpret_cast<const int4*>(Vtp + (size_t)sRow * T_ + sOff);

    for (int kt = 0; kt < T_; kt += 64) {
        __syncthreads();   // previous tile's LDS reads done
        *reinterpret_cast<int4*>(&Ks[sRow][sOff]) = kReg;
        *reinterpret_cast<int4*>(&Vs[sRow][sOff]) = vReg;
        __syncthreads();
        if (kt + 64 < T_) {   // issue next tile's loads; land under compute
            kReg = *reinterpret_cast<const int4*>(Kp + (size_t)(kt + 64 + sRow) * DH_ + sOff);
            vReg = *reinterpret_cast<const int4*>(Vtp + (size_t)sRow * T_ + kt + 64 + sOff);
        }

        // ---- S = Q K^T ----
        f32x4 s[4] = {};
#pragma unroll
        for (int ks = 0; ks < 2; ks++)
#pragma unroll
            for (int nj = 0; nj < 4; nj++) {
                bf16x8 kf = *reinterpret_cast<const bf16x8*>(&Ks[nj * 16 + lr][ks * 32 + lg * 8]);
                s[nj] = MFMA16(qf[ks], kf, s[nj]);
            }

        // ---- online softmax (rows 4*lg+rr, cols over nj x lr) ----
#pragma unroll
        for (int rr = 0; rr < 4; rr++) {
            float tmax = fmaxf(fmaxf(s[0][rr], s[1][rr]), fmaxf(s[2][rr], s[3][rr]));
#pragma unroll
            for (int off = 1; off < 16; off <<= 1)
                tmax = fmaxf(tmax, __shfl_xor(tmax, off));
            float mold = m_r[rr];
            bool keep = (tmax <= mold + 8.f);   // defer-max: skip rescale pass
            float m_use = keep ? mold : tmax;
            m_r[rr] = m_use;
            if (!keep) {
                float scl = exp2f((mold - m_use) * LOG2E);
                l_r[rr] *= scl;
#pragma unroll
                for (int dj = 0; dj < 4; dj++)
                    o_acc[dj][rr] *= scl;
            }
            float tsum = 0.f;
#pragma unroll
            for (int nj = 0; nj < 4; nj++) {
                float p = exp2f((s[nj][rr] - m_use) * LOG2E);
                s[nj][rr] = p;
                tsum += p;
            }
#pragma unroll
            for (int off = 1; off < 16; off <<= 1)
                tsum += __shfl_xor(tsum, off);
            l_r[rr] += tsum;
        }

        // ---- P -> LDS (A-operand layout re-entry) ----
#pragma unroll
        for (int nj = 0; nj < 4; nj++)
#pragma unroll
            for (int rr = 0; rr < 4; rr++)
                Ps[wv][lg * 4 + rr][nj * 16 + lr] = f2bf(s[nj][rr]);

        // ---- O += P V ----
#pragma unroll
        for (int ks = 0; ks < 2; ks++) {
            bf16x8 pf = *reinterpret_cast<const bf16x8*>(&Ps[wv][lr][ks * 32 + lg * 8]);
#pragma unroll
            for (int dj = 0; dj < 4; dj++) {
                bf16x8 vf = *reinterpret_cast<const bf16x8*>(&Vs[dj * 16 + lr][ks * 32 + lg * 8]);
                o_acc[dj] = MFMA16(pf, vf, o_acc[dj]);
            }
        }
    }

    // ---- normalize, O -> LDS ----
#pragma unroll
    for (int rr = 0; rr < 4; rr++) {
        float inv = 1.f / l_r[rr];
#pragma unroll
        for (int dj = 0; dj < 4; dj++)
            Ps[wv][lg * 4 + rr][dj * 16 + lr] = f2bf(o_acc[dj][rr] * inv);
    }

    // ---- Y = O @ Wo[h] ----
    f32x4 y[4] = {};
#pragma unroll
    for (int ks = 0; ks < 2; ks++) {
        bf16x8 of = *reinterpret_cast<const bf16x8*>(&Ps[wv][lr][ks * 32 + lg * 8]);
#pragma unroll
        for (int ej = 0; ej < 4; ej++) {
            bf16x8 wf = *reinterpret_cast<const bf16x8*>(&Wos[ej * 16 + lr][ks * 32 + lg * 8]);
            y[ej] = MFMA16(of, wf, y[ej]);
        }
    }

    // ---- bias + store fp32 out[b][t][h*64+e] ----
#pragma unroll
    for (int ej = 0; ej < 4; ej++) {
        float bias = bo[(h << 6) + ej * 16 + lr];
#pragma unroll
        for (int rr = 0; rr < 4; rr++) {
            int t = qrow0 + lg * 4 + rr;
            out[((size_t)b * T_ + t) * (H_ * DH_) + (h << 6) + ej * 16 + lr] =
                y[ej][rr] + bias;
        }
    }
}

// ---------------------------------------------------------------------------
extern "C" void kernel_launch(void* const* d_in, const int* in_sizes, int n_in,
                              void* d_out, int out_size, void* d_ws, size_t ws_size,
                              hipStream_t stream) {
    const float* x   = (const float*)d_in[0];
    const float* Wq  = (const float*)d_in[1];
    const float* Wkv = (const float*)d_in[2];
    const float* Wo  = (const float*)d_in[3];
    const float* bo  = (const float*)d_in[4];
    float* out = (float*)d_out;

    char* ws = (char*)d_ws;
    unsigned short* xb  = (unsigned short*)(ws);                  //  8 MB  x bf16
    unsigned short* wt  = (unsigned short*)(ws + 8388608);        //  6 MB  [Wq^T;Wkv^T]
    unsigned short* wot = (unsigned short*)(ws + 14680064);       // 128 KB Wo^T
    unsigned short* qb  = (unsigned short*)(ws + 14811136);       //  8 MB  Q   [b][h][t][d]
    unsigned short* kb  = (unsigned short*)(ws + 23199744);       //  8 MB  K   [b][h][t][d]
    unsigned short* vt  = (unsigned short*)(ws + 31588352);       //  8 MB  V^T [b][h][d][t]

    cvt_x_kernel<<<4096, 256, 0, stream>>>(x, xb, (B_ * T_ * DIM_) / 4);
    // Wq cols pre-scaled by DH^-0.5 = 0.125 (exact in bf16)
    transpose_cvt_kernel<<<dim3(32, 32), 256, 0, stream>>>(Wq, wt, DIM_, 1024, 0.125f);
    transpose_cvt_kernel<<<dim3(64, 32), 256, 0, stream>>>(Wkv, wt + 1024 * 1024, DIM_, 2048, 1.0f);
    cvt_wo_kernel<<<256, 256, 0, stream>>>(Wo, wot);
    qkv_gemm_kernel<<<768, 256, 0, stream>>>(xb, wt, qb, kb, vt);
    attn_kernel<<<512, 512, 0, stream>>>(qb, kb, vt, wot, bo, out);
}